// Round 1
// baseline (123.386 us; speedup 1.0000x reference)
//
#include <hip/hip_runtime.h>
#include <hip/hip_bf16.h>

typedef unsigned short ushort_t;
typedef __bf16 bf16_t;
typedef bf16_t bf16x8 __attribute__((ext_vector_type(8)));
typedef unsigned short u16x8v __attribute__((ext_vector_type(8)));
typedef float f32x4 __attribute__((ext_vector_type(4)));

#define D 128
#define NB 8
#define DFFN 512
#define TPB 16        // tokens per block
#define MROWS 128     // TPB*NB
#define FCH 64        // f-chunk
#define NCH 8         // DFFN/FCH
#define LN_EPS 1e-5f

__device__ __forceinline__ ushort_t bf16_rne(float f) {
  union { float f; unsigned u; } c; c.f = f;
  unsigned u = c.u;
  unsigned r = (u + 0x7FFFu + ((u >> 16) & 1u)) >> 16;
  return (ushort_t)r;
}

__device__ __forceinline__ bf16x8 loadfrag_bf(const ushort_t* p) {
  u16x8v v = *(const u16x8v*)p;
  return __builtin_bit_cast(bf16x8, v);
}

__device__ __forceinline__ bf16x8 load8_cvt(const float* p) {
  f32x4 a = *(const f32x4*)p;
  f32x4 b = *(const f32x4*)(p + 4);
  u16x8v r;
  r[0] = bf16_rne(a[0]); r[1] = bf16_rne(a[1]);
  r[2] = bf16_rne(a[2]); r[3] = bf16_rne(a[3]);
  r[4] = bf16_rne(b[0]); r[5] = bf16_rne(b[1]);
  r[6] = bf16_rne(b[2]); r[7] = bf16_rne(b[3]);
  return __builtin_bit_cast(bf16x8, r);
}

__device__ __forceinline__ f32x4 mfma16(bf16x8 a, bf16x8 b, f32x4 c) {
  return __builtin_amdgcn_mfma_f32_16x16x32_bf16(a, b, c, 0, 0, 0);
}

// Convert the three FFN weight matrices fp32 -> bf16 once per launch.
__global__ void cvt_weights(const float* __restrict__ wg,
                            const float* __restrict__ wu,
                            const float* __restrict__ wd,
                            ushort_t* __restrict__ o) {
  int i = blockIdx.x * 256 + threadIdx.x;   // 0 .. 3*512*128-1
  const int n1 = DFFN * D;                  // 65536
  float v;
  if (i < n1)            v = wg[i];
  else if (i < 2 * n1)   v = wu[i - n1];
  else                   v = wd[i - 2 * n1];
  o[i] = bf16_rne(v);
}

template <bool WS_BF16>
__global__ __launch_bounds__(256, 2)
void fused_geo_ffn(const float* __restrict__ x,
                   const float* __restrict__ iw,
                   const float* __restrict__ geo_gate,
                   const float* __restrict__ ln_w,
                   const float* __restrict__ ln_b,
                   const float* __restrict__ w_gate_f,
                   const float* __restrict__ w_up_f,
                   const float* __restrict__ w_down_f,
                   const float* __restrict__ cayley,
                   const ushort_t* __restrict__ wg_bf,
                   const ushort_t* __restrict__ wu_bf,
                   const ushort_t* __restrict__ wd_bf,
                   float* __restrict__ out) {
  __shared__ float sg[64];
  __shared__ ushort_t A_lds[MROWS * 128];   // normed, bf16, swizzled (32KB)
  __shared__ ushort_t H_lds[MROWS * FCH];   // h chunk, bf16, swizzled (16KB)

  const int tid = threadIdx.x;
  const int w = tid >> 6;       // wave 0..3
  const int l = tid & 63;       // lane
  const int lg = l >> 4;        // lane quarter-group 0..3
  const int ln16 = l & 15;
  const int kbase = lg * 8;

  // --- per-block sign*sigmoid table: sg[i*8+j] = cayley_sign(i,j)*sigmoid(iw[i][j]) ---
  if (tid < 64) {
    int i = tid >> 3, j = tid & 7;
    float s = cayley[(i * 8 + j) * 8 + (i ^ j)];
    float wv = iw[i * 8 + j];
    sg[tid] = s / (1.0f + __expf(-wv));
  }
  __syncthreads();

  float sgr[64];
#pragma unroll
  for (int t = 0; t < 64; ++t) sgr[t] = sg[t];

  const float gate = 1.0f / (1.0f + __expf(-geo_gate[0]));
  const float2 lw = *(const float2*)(ln_w + 2 * l);
  const float2 lb = *(const float2*)(ln_b + 2 * l);

  const long tok0 = (long)blockIdx.x * TPB;

  // ================= Phase 1: geo product + gate + LayerNorm -> A_lds (bf16) ========
  // wave w handles tokens w*4 .. w*4+3; lane l holds d = 2l, 2l+1
  for (int tt = 0; tt < 4; ++tt) {
    int ltok = w * 4 + tt;
    const float* xp = x + (tok0 + ltok) * (long)(NB * D);
    float2 xv[8];
#pragma unroll
    for (int i = 0; i < 8; ++i) xv[i] = *(const float2*)(xp + i * D + 2 * l);
#pragma unroll
    for (int k = 0; k < 8; ++k) {
      float2 g; g.x = 0.f; g.y = 0.f;
#pragma unroll
      for (int i = 0; i < 8; ++i) {
        float s = sgr[i * 8 + (i ^ k)];
        g.x += s * xv[i].x * xv[i ^ k].x;
        g.y += s * xv[i].y * xv[i ^ k].y;
      }
      float2 m;
      m.x = gate * g.x + (1.0f - gate) * xv[k].x;
      m.y = gate * g.y + (1.0f - gate) * xv[k].y;
      // LayerNorm over 128 d's: wave butterfly reduce of (sum, sumsq)
      float s1 = m.x + m.y;
      float s2 = m.x * m.x + m.y * m.y;
#pragma unroll
      for (int off = 32; off; off >>= 1) {
        s1 += __shfl_xor(s1, off, 64);
        s2 += __shfl_xor(s2, off, 64);
      }
      float mu = s1 * (1.0f / 128.0f);
      float var = s2 * (1.0f / 128.0f) - mu * mu;
      float rs = rsqrtf(var + LN_EPS);
      float nx = (m.x - mu) * rs * lw.x + lb.x;
      float ny = (m.y - mu) * rs * lw.y + lb.y;
      int row = ltok * 8 + k;
      int col = (2 * l) ^ ((row & 7) << 3);   // XOR swizzle (16B granule)
      unsigned pack = (unsigned)bf16_rne(nx) | ((unsigned)bf16_rne(ny) << 16);
      *(unsigned*)&A_lds[row * 128 + col] = pack;
    }
  }
  __syncthreads();

  // ================= Phase 2: SwiGLU FFN via MFMA ===================================
  f32x4 oacc[8][2];
#pragma unroll
  for (int mt = 0; mt < 8; ++mt)
#pragma unroll
    for (int nt = 0; nt < 2; ++nt)
#pragma unroll
      for (int r = 0; r < 4; ++r) oacc[mt][nt][r] = 0.f;

  for (int ch = 0; ch < NCH; ++ch) {
    // ---- GEMM1: G = normed @ Wg^T, U = normed @ Wu^T for this f-chunk -------------
    // waves split N: wave w owns f in [ch*64 + w*16, +16)
    f32x4 gacc[8], uacc[8];
#pragma unroll
    for (int mt = 0; mt < 8; ++mt)
#pragma unroll
      for (int r = 0; r < 4; ++r) { gacc[mt][r] = 0.f; uacc[mt][r] = 0.f; }

    const int fbase = ch * FCH + w * 16 + ln16;   // B-frag row (f)
    bf16x8 bg[4], bu[4];
#pragma unroll
    for (int ks = 0; ks < 4; ++ks) {
      int koff = ks * 32 + kbase;
      if (WS_BF16) {
        bg[ks] = loadfrag_bf(wg_bf + fbase * 128 + koff);
        bu[ks] = loadfrag_bf(wu_bf + fbase * 128 + koff);
      } else {
        bg[ks] = load8_cvt(w_gate_f + fbase * 128 + koff);
        bu[ks] = load8_cvt(w_up_f + fbase * 128 + koff);
      }
    }
#pragma unroll
    for (int mt = 0; mt < 8; ++mt) {
#pragma unroll
      for (int ks = 0; ks < 4; ++ks) {
        int row = mt * 16 + ln16;
        int col = (ks * 32 + kbase) ^ ((row & 7) << 3);
        bf16x8 a = *(const bf16x8*)&A_lds[row * 128 + col];
        gacc[mt] = mfma16(a, bg[ks], gacc[mt]);
        uacc[mt] = mfma16(a, bu[ks], uacc[mt]);
      }
    }
    // ---- h = silu(g)*u -> H_lds (bf16, swizzled) ----------------------------------
#pragma unroll
    for (int mt = 0; mt < 8; ++mt) {
#pragma unroll
      for (int r = 0; r < 4; ++r) {
        float gv = gacc[mt][r], uv = uacc[mt][r];
        float hv = gv / (1.0f + __expf(-gv)) * uv;
        int row = mt * 16 + lg * 4 + r;
        int col = (w * 16 + ln16) ^ ((row & 7) << 3);
        H_lds[row * FCH + col] = bf16_rne(hv);
      }
    }
    __syncthreads();
    // ---- GEMM2: O += H @ Wd^T ; waves split d: wave w owns d in [w*32, +32) -------
    bf16x8 b2[2][2];
#pragma unroll
    for (int nt = 0; nt < 2; ++nt) {
      int dcol = w * 32 + nt * 16 + ln16;
#pragma unroll
      for (int ks = 0; ks < 2; ++ks) {
        int foff = ch * FCH + ks * 32 + kbase;
        if (WS_BF16) b2[nt][ks] = loadfrag_bf(wd_bf + dcol * DFFN + foff);
        else         b2[nt][ks] = load8_cvt(w_down_f + dcol * DFFN + foff);
      }
    }
#pragma unroll
    for (int mt = 0; mt < 8; ++mt) {
#pragma unroll
      for (int ks = 0; ks < 2; ++ks) {
        int row = mt * 16 + ln16;
        int col = (ks * 32 + kbase) ^ ((row & 7) << 3);
        bf16x8 a2 = *(const bf16x8*)&H_lds[row * FCH + col];
        oacc[mt][0] = mfma16(a2, b2[0][ks], oacc[mt][0]);
        oacc[mt][1] = mfma16(a2, b2[1][ks], oacc[mt][1]);
      }
    }
    __syncthreads();
  }

  // ================= Epilogue: out = x + O ==========================================
#pragma unroll
  for (int mt = 0; mt < 8; ++mt) {
#pragma unroll
    for (int nt = 0; nt < 2; ++nt) {
#pragma unroll
      for (int r = 0; r < 4; ++r) {
        long row = tok0 * NB + mt * 16 + lg * 4 + r;
        int d = w * 32 + nt * 16 + ln16;
        long idx = row * D + d;
        out[idx] = x[idx] + oacc[mt][nt][r];
      }
    }
  }
}

extern "C" void kernel_launch(void* const* d_in, const int* in_sizes, int n_in,
                              void* d_out, int out_size, void* d_ws, size_t ws_size,
                              hipStream_t stream) {
  const float* x   = (const float*)d_in[0];
  const float* iw  = (const float*)d_in[1];
  const float* gg  = (const float*)d_in[2];
  const float* lnw = (const float*)d_in[3];
  const float* lnb = (const float*)d_in[4];
  const float* wg  = (const float*)d_in[5];
  const float* wu  = (const float*)d_in[6];
  const float* wd  = (const float*)d_in[7];
  const float* cs  = (const float*)d_in[8];
  float* out = (float*)d_out;

  int ntok = in_sizes[0] / (NB * D);
  int nblk = ntok / TPB;

  const int wtot = 3 * DFFN * D;   // 196608 bf16 elems = 384KB
  bool use_ws = ws_size >= (size_t)wtot * sizeof(ushort_t);
  if (use_ws) {
    ushort_t* wbf = (ushort_t*)d_ws;
    cvt_weights<<<wtot / 256, 256, 0, stream>>>(wg, wu, wd, wbf);
    fused_geo_ffn<true><<<nblk, 256, 0, stream>>>(
        x, iw, gg, lnw, lnb, wg, wu, wd, cs,
        wbf, wbf + DFFN * D, wbf + 2 * DFFN * D, out);
  } else {
    fused_geo_ffn<false><<<nblk, 256, 0, stream>>>(
        x, iw, gg, lnw, lnb, wg, wu, wd, cs,
        (const ushort_t*)nullptr, (const ushort_t*)nullptr, (const ushort_t*)nullptr, out);
  }
}